// Round 5
// baseline (189.717 us; speedup 1.0000x reference)
//
#include <hip/hip_runtime.h>
#include <stdint.h>

#define HID 128
#define BPB 16  // batch elements (waves) per block; block = 1024 threads

typedef float v2f __attribute__((ext_vector_type(2)));

// Full-wave64 f32 sum via DPP (VALU pipe, no LDS). Totals land in lane 63.
__device__ __forceinline__ void wave_reduce_add2(float& a, float& b) {
  asm("v_add_f32 %0, %0, %0 row_shr:1 bound_ctrl:0\n\t"
      "v_add_f32 %1, %1, %1 row_shr:1 bound_ctrl:0\n\t"
      "v_add_f32 %0, %0, %0 row_shr:2 bound_ctrl:0\n\t"
      "v_add_f32 %1, %1, %1 row_shr:2 bound_ctrl:0\n\t"
      "v_add_f32 %0, %0, %0 row_shr:4 bound_ctrl:0\n\t"
      "v_add_f32 %1, %1, %1 row_shr:4 bound_ctrl:0\n\t"
      "v_add_f32 %0, %0, %0 row_shr:8 bound_ctrl:0\n\t"
      "v_add_f32 %1, %1, %1 row_shr:8 bound_ctrl:0\n\t"
      "v_add_f32 %0, %0, %0 row_bcast:15 row_mask:0xa\n\t"
      "v_add_f32 %1, %1, %1 row_bcast:15 row_mask:0xa\n\t"
      "v_add_f32 %0, %0, %0 row_bcast:31 row_mask:0xc\n\t"
      "v_add_f32 %1, %1, %1 row_bcast:31 row_mask:0xc\n\t"
      : "+v"(a), "+v"(b));
}

__global__ __launch_bounds__(1024, 4) void lsnn_fwd(
    const float* __restrict__ x,      // (B,4)
    const float* __restrict__ w_in,   // (128,8)
    const float* __restrict__ w_rec,  // (128,128)
    const float* __restrict__ w_out,  // (2,128)
    float* __restrict__ out,          // (B,2)
    int B)
{
#pragma clang fp contract(off)
  // Transposed recurrent weights: wt[k][l] = (w_rec[l][k], w_rec[l+64][k]).
  // Per spiking k (wave-uniform scalar), lanes read 512 contiguous bytes ->
  // conflict-free ds_read_b64.
  __shared__ float2 wt[HID * 64];

  const int tid = threadIdx.x;
#pragma unroll
  for (int m = 0; m < 8; ++m) {
    int idx = m * 1024 + tid;
    int l = idx & 63;   // lane-fast -> contiguous LDS stores (conflict-free)
    int k = idx >> 6;   // 0..127 presynaptic
    wt[(k << 6) | l] = make_float2(w_rec[l * HID + k], w_rec[(l + 64) * HID + k]);
  }
  __syncthreads();

  const int lane = tid & 63;
  const int b = blockIdx.x * BPB + (tid >> 6);
  if (b >= B) return;

  const int j0 = lane;
  const int j1 = lane + 64;
  const v2f zero2 = {0.0f, 0.0f};

  // ---------- encoder: 4 effective channels (pos/neg mutually exclusive) ---
  float cc[4], ev[4];
  v2f wsel[4];
  {
#pragma unroll
    for (int c = 0; c < 4; ++c) {
      float p = 50.0f * x[b * 4 + c];
      cc[c] = fabsf(p);
      ev[c] = 0.0f;
      int col = (p > 0.0f) ? c : (c + 4);
      wsel[c].x = w_in[j0 * 8 + col];
      wsel[c].y = w_in[j1 * 8 + col];
    }
  }

  // 40 steps x 4 channel-bits, one byte per step; encoder state is identical
  // across lanes of the wave -> hoist packed words into SGPRs.
  uint32_t spk[10];
#pragma unroll
  for (int tw = 0; tw < 5; ++tw) {
    uint32_t lo = 0, hi = 0;
    for (int ts = 0; ts < 8; ++ts) {
      unsigned byte = 0;
#pragma unroll
      for (int c = 0; c < 4; ++c) {
        ev[c] = ev[c] + 0.1f * (cc[c] - ev[c]);
        if (ev[c] - 1.0f > 0.0f) {
          byte |= (1u << c);
          ev[c] = 0.0f;
        }
      }
      if (ts < 4) lo |= byte << (ts << 3);
      else        hi |= byte << ((ts - 4) << 3);
    }
    spk[2 * tw] = __builtin_amdgcn_readfirstlane((int)lo);
    spk[2 * tw + 1] = __builtin_amdgcn_readfirstlane((int)hi);
  }

  v2f wop0, wop1;  // (w_out[0][j], w_out[1][j]) for j0 and j1
  wop0.x = w_out[j0];  wop0.y = w_out[HID + j0];
  wop1.x = w_out[j1];  wop1.y = w_out[HID + j1];

  // ---------- state (packed pairs) ----------
  v2f vv = zero2, ii = zero2, io = zero2, vo = zero2;
  v2f bb = {1.0f, 1.0f};
  v2f mm = {-INFINITY, -INFINITY};
  uint32_t zw[4] = {0u, 0u, 0u, 0u};  // spike mask words (SGPR, uniform)

  const char* wtb = (const char*)wt;
  const int vb = lane << 3;  // per-lane float2 byte base within a k-row

  // ---------- T=40 recurrent steps, fully unrolled ----------
#pragma unroll
  for (int t = 0; t < 40; ++t) {
    const int xb = (int)((spk[t >> 2] >> ((t & 3) << 3)) & 0xFu);

    v2f vd = vv + 0.1f * (ii - vv);
    v2f id = ii - 0.2f * ii;
    v2f one_minus_b = {1.0f - bb.x, 1.0f - bb.y};
    v2f bd = bb + 1.4285714285714286e-06f * one_minus_b;
    bool z0 = (vd.x - bd.x) > 0.0f;
    bool z1 = (vd.y - bd.y) > 0.0f;
    uint64_t nz0 = __ballot(z0);
    uint64_t nz1 = __ballot(z1);
    vv.x = z0 ? 0.0f : vd.x;
    vv.y = z1 ? 0.0f : vd.y;
    bb.x = bd.x + (z0 ? 0.0025714285714285714f : 0.0f);
    bb.y = bd.y + (z1 ? 0.0025714285714285714f : 0.0f);

    // readout projection of z_new: DPP wave-reduce (valid in lane 63 only)
    v2f pp = (z0 ? wop0 : zero2) + (z1 ? wop1 : zero2);
    float p0 = pp.x, p1 = pp.y;
    wave_reduce_add2(p0, p1);

    // LI readout (vo uses OLD io), running max — valid in lane 63 only
    v2f von = vo + 0.1f * (io - vo);
    v2f pv; pv.x = p0; pv.y = p1;
    io = (io - 0.2f * io) + pv;
    vo = von;
    mm.x = fmaxf(mm.x, von.x);
    mm.y = fmaxf(mm.y, von.y);

    // input current from encoder spikes (xb is an SGPR -> uniform branches)
    v2f ai = zero2;
    if (xb & 1) ai += wsel[0];
    if (xb & 2) ai += wsel[1];
    if (xb & 4) ai += wsel[2];
    if (xb & 8) ai += wsel[3];

    // recurrent current from OLD z: depth-2 software-pipelined sparse loop.
    // One conflict-free ds_read_b64 + one v_pk_add_f32 per spiking k,
    // ascending k (reference accumulation order preserved): load for spike
    // i+1 is issued before the accumulate of spike i (hides LDS latency).
    v2f ar = zero2;
#pragma unroll
    for (int wword = 0; wword < 4; ++wword) {
      const int kbase = wword << 5;  // fold word base into the scalar shift
      uint32_t m = zw[wword];
      if (m) {
        int k = __builtin_ctz(m); m &= m - 1;
        v2f w0 = *(const v2f*)(wtb + ((((kbase + k) << 9)) | vb));
        while (m) {
          int k2 = __builtin_ctz(m); m &= m - 1;
          v2f w1 = *(const v2f*)(wtb + ((((kbase + k2) << 9)) | vb));
          ar += w0;   // overlaps w1's LDS latency (lgkmcnt(1))
          w0 = w1;
        }
        ar += w0;
      }
    }

    ii = (id + ai) + ar;

    zw[0] = (uint32_t)nz0;
    zw[1] = (uint32_t)(nz0 >> 32);
    zw[2] = (uint32_t)nz1;
    zw[3] = (uint32_t)(nz1 >> 32);
  }

  // ---------- softmax over the 2 per-batch max-voltages (lane 63 valid) ----
  if (lane == 63) {
    float mx = fmaxf(mm.x, mm.y);
    float e0 = expf(mm.x - mx);
    float e1 = expf(mm.y - mx);
    float s = e0 + e1;
    out[b * 2 + 0] = e0 / s;
    out[b * 2 + 1] = e1 / s;
  }
}

extern "C" void kernel_launch(void* const* d_in, const int* in_sizes, int n_in,
                              void* d_out, int out_size, void* d_ws, size_t ws_size,
                              hipStream_t stream) {
  (void)n_in; (void)out_size; (void)d_ws; (void)ws_size;
  const float* x = (const float*)d_in[0];
  const float* w_in = (const float*)d_in[1];
  const float* w_rec = (const float*)d_in[2];
  const float* w_out = (const float*)d_in[3];
  float* out = (float*)d_out;
  int B = in_sizes[0] / 4;
  int blocks = (B + BPB - 1) / BPB;
  lsnn_fwd<<<blocks, 1024, 0, stream>>>(x, w_in, w_rec, w_out, out, B);
}

// Round 6
// 156.586 us; speedup vs baseline: 1.2116x; 1.2116x over previous
//
#include <hip/hip_runtime.h>
#include <stdint.h>

#define HID 128
#define BPB 16  // batch elements (waves) per block; block = 1024 threads

typedef float v2f __attribute__((ext_vector_type(2)));

// Full-wave64 f32 sum via DPP (VALU pipe, no LDS). Totals land in lane 63.
__device__ __forceinline__ void wave_reduce_add2(float& a, float& b) {
  asm("v_add_f32 %0, %0, %0 row_shr:1 bound_ctrl:0\n\t"
      "v_add_f32 %1, %1, %1 row_shr:1 bound_ctrl:0\n\t"
      "v_add_f32 %0, %0, %0 row_shr:2 bound_ctrl:0\n\t"
      "v_add_f32 %1, %1, %1 row_shr:2 bound_ctrl:0\n\t"
      "v_add_f32 %0, %0, %0 row_shr:4 bound_ctrl:0\n\t"
      "v_add_f32 %1, %1, %1 row_shr:4 bound_ctrl:0\n\t"
      "v_add_f32 %0, %0, %0 row_shr:8 bound_ctrl:0\n\t"
      "v_add_f32 %1, %1, %1 row_shr:8 bound_ctrl:0\n\t"
      "v_add_f32 %0, %0, %0 row_bcast:15 row_mask:0xa\n\t"
      "v_add_f32 %1, %1, %1 row_bcast:15 row_mask:0xa\n\t"
      "v_add_f32 %0, %0, %0 row_bcast:31 row_mask:0xc\n\t"
      "v_add_f32 %1, %1, %1 row_bcast:31 row_mask:0xc\n\t"
      : "+v"(a), "+v"(b));
}

__global__ __launch_bounds__(1024, 4) void lsnn_fwd(
    const float* __restrict__ x,      // (B,4)
    const float* __restrict__ w_in,   // (128,8)
    const float* __restrict__ w_rec,  // (128,128)
    const float* __restrict__ w_out,  // (2,128)
    float* __restrict__ out,          // (B,2)
    int B)
{
#pragma clang fp contract(off)
  // Transposed recurrent weights: wt[k][l] = (w_rec[l][k], w_rec[l+64][k]).
  // Per spiking k (wave-uniform scalar), lanes read 512 contiguous bytes ->
  // conflict-free ds_read_b64.
  __shared__ float2 wt[HID * 64];

  const int tid = threadIdx.x;
#pragma unroll
  for (int m = 0; m < 8; ++m) {
    int idx = m * 1024 + tid;
    int l = idx & 63;   // lane-fast -> contiguous LDS stores (conflict-free)
    int k = idx >> 6;   // 0..127 presynaptic
    wt[(k << 6) | l] = make_float2(w_rec[l * HID + k], w_rec[(l + 64) * HID + k]);
  }
  __syncthreads();

  const int lane = tid & 63;
  const int b = blockIdx.x * BPB + (tid >> 6);
  if (b >= B) return;

  const int j0 = lane;
  const int j1 = lane + 64;
  const v2f zero2 = {0.0f, 0.0f};

  // ---------- encoder: 4 effective channels (pos/neg mutually exclusive) ---
  float cc[4], ev[4];
  v2f wsel[4];
  {
#pragma unroll
    for (int c = 0; c < 4; ++c) {
      float p = 50.0f * x[b * 4 + c];
      cc[c] = fabsf(p);
      ev[c] = 0.0f;
      int col = (p > 0.0f) ? c : (c + 4);
      wsel[c].x = w_in[j0 * 8 + col];
      wsel[c].y = w_in[j1 * 8 + col];
    }
  }

  // 40 steps x 4 channel-bits, one byte per step, 8 steps per 64-bit word.
  // Encoder state is identical across lanes -> hoist words into SGPRs.
  uint64_t spkw[5];
#pragma unroll
  for (int tw = 0; tw < 5; ++tw) {
    uint32_t lo = 0, hi = 0;
    for (int ts = 0; ts < 8; ++ts) {
      unsigned byte = 0;
#pragma unroll
      for (int c = 0; c < 4; ++c) {
        ev[c] = ev[c] + 0.1f * (cc[c] - ev[c]);
        if (ev[c] - 1.0f > 0.0f) {
          byte |= (1u << c);
          ev[c] = 0.0f;
        }
      }
      if (ts < 4) lo |= byte << (ts << 3);
      else        hi |= byte << ((ts - 4) << 3);
    }
    uint32_t slo = (uint32_t)__builtin_amdgcn_readfirstlane((int)lo);
    uint32_t shi = (uint32_t)__builtin_amdgcn_readfirstlane((int)hi);
    spkw[tw] = ((uint64_t)shi << 32) | slo;
  }

  v2f wop0, wop1;  // (w_out[0][j], w_out[1][j]) for j0 and j1
  wop0.x = w_out[j0];  wop0.y = w_out[HID + j0];
  wop1.x = w_out[j1];  wop1.y = w_out[HID + j1];

  // ---------- state (packed pairs) ----------
  v2f vv = zero2, ii = zero2, io = zero2, vo = zero2;
  v2f bb = {1.0f, 1.0f};
  v2f mm = {-INFINITY, -INFINITY};
  uint64_t zm0 = 0ull, zm1 = 0ull;

  const char* wtb = (const char*)wt;
  const int vb = lane << 3;  // per-lane float2 byte base within a k-row

  // ---------- T=40 recurrent steps: 5 unrolled words x 8 rolled steps ------
#pragma unroll
  for (int tw = 0; tw < 5; ++tw) {
    uint64_t cw = spkw[tw];  // SGPR pair; low nibble of each byte = step
#pragma unroll 1
    for (int ts = 0; ts < 8; ++ts) {
      const int xb = (int)(cw & 0xFull);
      cw >>= 8;

      v2f vd = vv + 0.1f * (ii - vv);
      v2f id = ii - 0.2f * ii;
      v2f one_minus_b = {1.0f - bb.x, 1.0f - bb.y};
      v2f bd = bb + 1.4285714285714286e-06f * one_minus_b;
      bool z0 = (vd.x - bd.x) > 0.0f;
      bool z1 = (vd.y - bd.y) > 0.0f;
      uint64_t nz0 = __ballot(z0);
      uint64_t nz1 = __ballot(z1);
      vv.x = z0 ? 0.0f : vd.x;
      vv.y = z1 ? 0.0f : vd.y;
      bb.x = bd.x + (z0 ? 0.0025714285714285714f : 0.0f);
      bb.y = bd.y + (z1 ? 0.0025714285714285714f : 0.0f);

      // readout projection of z_new: DPP wave-reduce (valid in lane 63 only)
      v2f pp = (z0 ? wop0 : zero2) + (z1 ? wop1 : zero2);
      float p0 = pp.x, p1 = pp.y;
      wave_reduce_add2(p0, p1);

      // LI readout (vo uses OLD io), running max — valid in lane 63 only
      v2f von = vo + 0.1f * (io - vo);
      v2f pv; pv.x = p0; pv.y = p1;
      io = (io - 0.2f * io) + pv;
      vo = von;
      mm.x = fmaxf(mm.x, von.x);
      mm.y = fmaxf(mm.y, von.y);

      // input current from encoder spikes (xb is an SGPR -> uniform branches)
      v2f ai = zero2;
      if (xb & 1) ai += wsel[0];
      if (xb & 2) ai += wsel[1];
      if (xb & 4) ai += wsel[2];
      if (xb & 8) ai += wsel[3];

      // recurrent current from OLD z: depth-2 software-pipelined sparse loop.
      // One conflict-free ds_read_b64 + one v_pk_add_f32 per spiking k,
      // strictly ascending k (reference accumulation order preserved); the
      // load for spike i+1 is issued before the accumulate of spike i, so
      // the accumulate waits on lgkmcnt(1) instead of lgkmcnt(0).
      v2f ar = zero2;
      {
        uint64_t m = zm0;
        if (m) {
          int k = __builtin_ctzll(m); m &= m - 1;
          v2f w0 = *(const v2f*)(wtb + ((k << 9) | vb));
          while (m) {
            int k2 = __builtin_ctzll(m); m &= m - 1;
            v2f w1 = *(const v2f*)(wtb + ((k2 << 9) | vb));
            ar += w0;
            w0 = w1;
          }
          ar += w0;
        }
        m = zm1;
        if (m) {
          int k = __builtin_ctzll(m); m &= m - 1;
          v2f w0 = *(const v2f*)(wtb + 32768 + ((k << 9) | vb));
          while (m) {
            int k2 = __builtin_ctzll(m); m &= m - 1;
            v2f w1 = *(const v2f*)(wtb + 32768 + ((k2 << 9) | vb));
            ar += w0;
            w0 = w1;
          }
          ar += w0;
        }
      }

      ii = (id + ai) + ar;

      zm0 = nz0;
      zm1 = nz1;
    }
  }

  // ---------- softmax over the 2 per-batch max-voltages (lane 63 valid) ----
  if (lane == 63) {
    float mx = fmaxf(mm.x, mm.y);
    float e0 = expf(mm.x - mx);
    float e1 = expf(mm.y - mx);
    float s = e0 + e1;
    out[b * 2 + 0] = e0 / s;
    out[b * 2 + 1] = e1 / s;
  }
}

extern "C" void kernel_launch(void* const* d_in, const int* in_sizes, int n_in,
                              void* d_out, int out_size, void* d_ws, size_t ws_size,
                              hipStream_t stream) {
  (void)n_in; (void)out_size; (void)d_ws; (void)ws_size;
  const float* x = (const float*)d_in[0];
  const float* w_in = (const float*)d_in[1];
  const float* w_rec = (const float*)d_in[2];
  const float* w_out = (const float*)d_in[3];
  float* out = (float*)d_out;
  int B = in_sizes[0] / 4;
  int blocks = (B + BPB - 1) / BPB;
  lsnn_fwd<<<blocks, 1024, 0, stream>>>(x, w_in, w_rec, w_out, out, B);
}

// Round 7
// 143.313 us; speedup vs baseline: 1.3238x; 1.0926x over previous
//
#include <hip/hip_runtime.h>
#include <stdint.h>

#define HID 128
#define BPB 16  // batch elements (waves) per block; block = 1024 threads

// Full-wave64 f32 sum via DPP (VALU pipe, no LDS). Totals land in lane 63.
__device__ __forceinline__ void wave_reduce_add2(float& a, float& b) {
  asm("v_add_f32 %0, %0, %0 row_shr:1 bound_ctrl:0\n\t"
      "v_add_f32 %1, %1, %1 row_shr:1 bound_ctrl:0\n\t"
      "v_add_f32 %0, %0, %0 row_shr:2 bound_ctrl:0\n\t"
      "v_add_f32 %1, %1, %1 row_shr:2 bound_ctrl:0\n\t"
      "v_add_f32 %0, %0, %0 row_shr:4 bound_ctrl:0\n\t"
      "v_add_f32 %1, %1, %1 row_shr:4 bound_ctrl:0\n\t"
      "v_add_f32 %0, %0, %0 row_shr:8 bound_ctrl:0\n\t"
      "v_add_f32 %1, %1, %1 row_shr:8 bound_ctrl:0\n\t"
      "v_add_f32 %0, %0, %0 row_bcast:15 row_mask:0xa\n\t"
      "v_add_f32 %1, %1, %1 row_bcast:15 row_mask:0xa\n\t"
      "v_add_f32 %0, %0, %0 row_bcast:31 row_mask:0xc\n\t"
      "v_add_f32 %1, %1, %1 row_bcast:31 row_mask:0xc\n\t"
      : "+v"(a), "+v"(b));
}

__global__ __launch_bounds__(1024, 4) void lsnn_fwd(
    const float* __restrict__ x,      // (B,4)
    const float* __restrict__ w_in,   // (128,8)
    const float* __restrict__ w_rec,  // (128,128)
    const float* __restrict__ w_out,  // (2,128)
    float* __restrict__ out,          // (B,2)
    int B)
{
#pragma clang fp contract(off)
  // Transposed recurrent weights: wt[k][l'] = (w_rec[l][k], w_rec[l+64][k])
  // with l' = l ^ (k & 63). Per spiking k (uniform), lanes read contiguous
  // (permuted) float2 -> conflict-free ds_read_b64. 64 KiB.
  __shared__ float2 wt[HID * 64];

  const int tid = threadIdx.x;
#pragma unroll
  for (int m = 0; m < 8; ++m) {
    int idx = m * 1024 + tid;
    int k = idx & 127;        // presynaptic index (coalesced fast axis)
    int l = idx >> 7;         // postsynaptic pair index 0..63
    float a = w_rec[l * HID + k];
    float c = w_rec[(l + 64) * HID + k];
    wt[(k << 6) | (l ^ (k & 63))] = make_float2(a, c);
  }
  __syncthreads();

  const int lane = tid & 63;
  const int b = blockIdx.x * BPB + (tid >> 6);
  if (b >= B) return;

  const int j0 = lane;
  const int j1 = lane + 64;

  // ---------- encoder: 4 effective channels (pos/neg mutually exclusive) ---
  float cc[4], ev[4];
  float wsel0[4], wsel1[4];
  {
#pragma unroll
    for (int c = 0; c < 4; ++c) {
      float p = 50.0f * x[b * 4 + c];
      cc[c] = fabsf(p);
      ev[c] = 0.0f;
      int col = (p > 0.0f) ? c : (c + 4);
      wsel0[c] = w_in[j0 * 8 + col];
      wsel1[c] = w_in[j1 * 8 + col];
    }
  }

  uint64_t pk[5];  // 40 steps x 4 channel-bits, one byte per step
#pragma unroll
  for (int tw = 0; tw < 5; ++tw) {
    uint64_t pw = 0;
    for (int ts = 0; ts < 8; ++ts) {
      unsigned byte = 0;
#pragma unroll
      for (int c = 0; c < 4; ++c) {
        ev[c] = ev[c] + 0.1f * (cc[c] - ev[c]);
        if (ev[c] - 1.0f > 0.0f) {
          byte |= (1u << c);
          ev[c] = 0.0f;
        }
      }
      pw |= ((uint64_t)byte) << (ts << 3);
    }
    pk[tw] = pw;
  }

  const float wo00 = w_out[j0], wo01 = w_out[j1];
  const float wo10 = w_out[HID + j0], wo11 = w_out[HID + j1];

  // ---------- state ----------
  float v0 = 0.f, v1 = 0.f, i0 = 0.f, i1 = 0.f, b0 = 1.0f, b1 = 1.0f;
  float io0 = 0.f, io1 = 0.f, vo0 = 0.f, vo1 = 0.f;
  float mm0 = -INFINITY, mm1 = -INFINITY;
  uint64_t zm0 = 0ull, zm1 = 0ull;

  const char* wtb = (const char*)wt;
  const int vb = lane << 3;  // per-lane float2 byte base; XOR'ed with k-offset

  // ---------- T=40 recurrent steps (5 words x 8 steps, static pk index) ----
#pragma unroll
  for (int tw = 0; tw < 5; ++tw) {
    uint64_t pw = pk[tw];
    for (int ts = 0; ts < 8; ++ts) {
      // recurrent current from PREVIOUS step's z, hoisted to the top so the
      // LDS reads overlap the independent state-update / DPP VALU work.
      // One conflict-free ds_read_b64 per spiking k, ascending k
      // (reference accumulation order preserved -> bit-exact).
      float ar0 = 0.f, ar1 = 0.f;
      uint64_t m0 = zm0;
      while (m0) {
        int k = __builtin_ctzll(m0);
        m0 &= m0 - 1;
        int soff = k * 520;  // (k<<9)|(k<<3), disjoint bit fields
        float2 w = *(const float2*)(wtb + (vb ^ soff));
        ar0 += w.x;
        ar1 += w.y;
      }
      uint64_t m1 = zm1;
      while (m1) {
        int k = __builtin_ctzll(m1);
        m1 &= m1 - 1;
        int soff = 32768 + k * 520;  // ((64+k)<<9)|(k<<3)
        float2 w = *(const float2*)(wtb + (vb ^ soff));
        ar0 += w.x;
        ar1 += w.y;
      }

      // ---- membrane / adaptation state update (bit-exact path) ----
      float vd0 = v0 + 0.1f * (i0 - v0);
      float vd1 = v1 + 0.1f * (i1 - v1);
      float id0 = i0 - 0.2f * i0;
      float id1 = i1 - 0.2f * i1;
      float bd0 = b0 + 1.4285714285714286e-06f * (1.0f - b0);
      float bd1 = b1 + 1.4285714285714286e-06f * (1.0f - b1);
      bool z0 = (vd0 - bd0) > 0.0f;
      bool z1 = (vd1 - bd1) > 0.0f;
      v0 = z0 ? 0.0f : vd0;
      v1 = z1 ? 0.0f : vd1;
      b0 = bd0 + (z0 ? 0.0025714285714285714f : 0.0f);
      b1 = bd1 + (z1 ? 0.0025714285714285714f : 0.0f);

      // readout projection of z_new: DPP wave-reduce (valid in lane 63 only)
      float p0 = (z0 ? wo00 : 0.0f) + (z1 ? wo01 : 0.0f);
      float p1 = (z0 ? wo10 : 0.0f) + (z1 ? wo11 : 0.0f);
      wave_reduce_add2(p0, p1);

      // LI readout (vo uses OLD io), fma-form (readout path: no feedback
      // into spikes, so fused rounding is safe). Valid in lane 63 only.
      float von0 = __builtin_fmaf(0.1f, io0, 0.9f * vo0);
      float von1 = __builtin_fmaf(0.1f, io1, 0.9f * vo1);
      io0 = __builtin_fmaf(0.8f, io0, p0);
      io1 = __builtin_fmaf(0.8f, io1, p1);
      vo0 = von0;
      vo1 = von1;
      mm0 = fmaxf(mm0, von0);
      mm1 = fmaxf(mm1, von1);

      // input current from encoder spikes (nibble identical across lanes)
      int xb = (int)((pw >> (ts << 3)) & 0xFF);
      float ai0 = 0.f, ai1 = 0.f;
#pragma unroll
      for (int c = 0; c < 4; ++c) {
        if (xb & (1 << c)) {
          ai0 += wsel0[c];
          ai1 += wsel1[c];
        }
      }

      i0 = (id0 + ai0) + ar0;
      i1 = (id1 + ai1) + ar1;

      zm0 = __ballot(z0);
      zm1 = __ballot(z1);
    }
  }

  // ---------- softmax over the 2 per-batch max-voltages (lane 63 valid) ----
  if (lane == 63) {
    float mx = fmaxf(mm0, mm1);
    float e0 = expf(mm0 - mx);
    float e1 = expf(mm1 - mx);
    float s = e0 + e1;
    out[b * 2 + 0] = e0 / s;
    out[b * 2 + 1] = e1 / s;
  }
}

extern "C" void kernel_launch(void* const* d_in, const int* in_sizes, int n_in,
                              void* d_out, int out_size, void* d_ws, size_t ws_size,
                              hipStream_t stream) {
  (void)n_in; (void)out_size; (void)d_ws; (void)ws_size;
  const float* x = (const float*)d_in[0];
  const float* w_in = (const float*)d_in[1];
  const float* w_rec = (const float*)d_in[2];
  const float* w_out = (const float*)d_in[3];
  float* out = (float*)d_out;
  int B = in_sizes[0] / 4;
  int blocks = (B + BPB - 1) / BPB;
  lsnn_fwd<<<blocks, 1024, 0, stream>>>(x, w_in, w_rec, w_out, out, B);
}